// Round 2
// baseline (391.827 us; speedup 1.0000x reference)
//
#include <hip/hip_runtime.h>

// IFOPooling: h_t = f_t * h_{t-1} + i_t * z_t along S (contiguous axis).
// Layout [B=16, H=1024, S=2048] fp32.
//
// Round 2 structure: one WAVE per row (no barriers, no cross-wave phase).
// 4 waves/block, grid = rows/4. Each wave scans its row in 4 passes of 512
// elements; each lane owns a contiguous 8-element chunk (2x float4 at 32B
// lane stride -> paired instructions fully cover each 64B line, no
// over-fetch). Pass carry via __shfl broadcast from lane 63. Next-pass
// loads prefetched before the current pass's shuffle-scan chain.

constexpr int S_LEN  = 2048;
constexpr int WAVES  = 4;          // waves per block (independent rows)
constexpr int TPB    = 64 * WAVES;
constexpr int PASSES = 4;
constexpr int PASS_E = S_LEN / PASSES;   // 512 elements per pass

__global__ __launch_bounds__(TPB, 8) void ifo_scan_wave(
    const float* __restrict__ f,
    const float* __restrict__ z,
    const float* __restrict__ iin,
    float* __restrict__ out)
{
    const int lane = threadIdx.x & 63;
    const int wv   = threadIdx.x >> 6;
    const size_t row  = (size_t)blockIdx.x * WAVES + wv;
    const size_t base = row * S_LEN;

    const float4* F = reinterpret_cast<const float4*>(f   + base);
    const float4* Z = reinterpret_cast<const float4*>(z   + base);
    const float4* I = reinterpret_cast<const float4*>(iin + base);
    float4*       O = reinterpret_cast<float4*>(out + base);

    const int c0 = lane * 2;       // this lane's first float4 index in a pass
    const int c1 = lane * 2 + 1;
    const int pstride = PASS_E / 4;  // float4s per pass = 128

    // Preload pass 0
    float4 f0 = F[c0], f1 = F[c1];
    float4 z0 = Z[c0], z1 = Z[c1];
    float4 i0 = I[c0], i1 = I[c1];

    float H = 0.0f;  // carry into current pass (same value in all lanes)

    #pragma unroll
    for (int p = 0; p < PASSES; ++p) {
        // Prefetch next pass before entering the dependent scan chain
        float4 nf0, nf1, nz0, nz1, ni0, ni1;
        if (p + 1 < PASSES) {
            const int o = (p + 1) * pstride;
            nf0 = F[o + c0]; nf1 = F[o + c1];
            nz0 = Z[o + c0]; nz1 = Z[o + c1];
            ni0 = I[o + c0]; ni1 = I[o + c1];
        }

        float4 x0, x1;
        x0.x = i0.x * z0.x; x0.y = i0.y * z0.y;
        x0.z = i0.z * z0.z; x0.w = i0.w * z0.w;
        x1.x = i1.x * z1.x; x1.y = i1.y * z1.y;
        x1.z = i1.z * z1.z; x1.w = i1.w * z1.w;

        // Serial compose of this lane's 8-element chunk: h_out = a*h_in + b
        float a = f0.x, b = x0.x;
        a = f0.y * a;  b = f0.y * b + x0.y;
        a = f0.z * a;  b = f0.z * b + x0.z;
        a = f0.w * a;  b = f0.w * b + x0.w;
        a = f1.x * a;  b = f1.x * b + x1.x;
        a = f1.y * a;  b = f1.y * b + x1.y;
        a = f1.z * a;  b = f1.z * b + x1.z;
        a = f1.w * a;  b = f1.w * b + x1.w;

        // Wave-level inclusive scan under composition
        #pragma unroll
        for (int d = 1; d < 64; d <<= 1) {
            float a_up = __shfl_up(a, d);
            float b_up = __shfl_up(b, d);
            if (lane >= d) {
                b = a * b_up + b;
                a = a * a_up;
            }
        }

        // h entering this lane's chunk = (exclusive prefix) applied to H
        float ea = __shfl_up(a, 1);
        float eb = __shfl_up(b, 1);
        if (lane == 0) { ea = 1.0f; eb = 0.0f; }
        float h = ea * H + eb;

        // Replay chunk, store
        float4 o0, o1;
        h = f0.x * h + x0.x;  o0.x = h;
        h = f0.y * h + x0.y;  o0.y = h;
        h = f0.z * h + x0.z;  o0.z = h;
        h = f0.w * h + x0.w;  o0.w = h;
        h = f1.x * h + x1.x;  o1.x = h;
        h = f1.y * h + x1.y;  o1.y = h;
        h = f1.z * h + x1.z;  o1.z = h;
        h = f1.w * h + x1.w;  o1.w = h;

        const int o = p * pstride;
        O[o + c0] = o0;
        O[o + c1] = o1;

        // Carry to next pass: full-pass inclusive op applied to H
        float A63 = __shfl(a, 63);
        float B63 = __shfl(b, 63);
        H = A63 * H + B63;

        f0 = nf0; f1 = nf1;
        z0 = nz0; z1 = nz1;
        i0 = ni0; i1 = ni1;
    }
}

extern "C" void kernel_launch(void* const* d_in, const int* in_sizes, int n_in,
                              void* d_out, int out_size, void* d_ws, size_t ws_size,
                              hipStream_t stream) {
    const float* f = (const float*)d_in[0];
    const float* z = (const float*)d_in[1];
    const float* i = (const float*)d_in[2];
    float* out = (float*)d_out;

    const int rows = out_size / S_LEN;      // B*H = 16384
    ifo_scan_wave<<<rows / WAVES, TPB, 0, stream>>>(f, z, i, out);
}